// Round 2
// baseline (164.016 us; speedup 1.0000x reference)
//
#include <hip/hip_runtime.h>
#include <hip/hip_bf16.h>

// ParallelBERTGenerator: out = scores @ M + bc with
//   M = Wc1^T + prev @ Wc2^T  (scores never materialized)
//   out[b] = scale * query[b] @ P[b] + row[b]
//   P[b] = Wq^T @ N[b],  N[b] = Kz[b]^T @ M,  Kz = (key@Wk^T + bk) masked-to-zero
//   row[b][d] = bc[d] - 1e9 * sum_{masked k} M[k][d] + scale*(bq@N[b])[d]
// All GEMMs: NT (A [M][K], B [N][K], both K-major) bf16 MFMA 16x16x32,
// 128x128 tile, BK=32, global_load_lds(16B). Mask-constant path kept fp32.

typedef __attribute__((ext_vector_type(8))) short short8;
typedef __attribute__((ext_vector_type(4))) float f32x4;

#define SCALE 0.03608439182435161f   /* 1/sqrt(768) */

__device__ inline unsigned short f2bf(float x) {
  unsigned int u = __builtin_bit_cast(unsigned int, x);
  u = (u + 0x7fffu + ((u >> 16) & 1u)) >> 16;   // RNE
  return (unsigned short)u;
}
__device__ inline float bf2f(unsigned short h) {
  return __builtin_bit_cast(float, ((unsigned int)h) << 16);
}

// ---------------- conversion kernels ----------------
__global__ void k_cvt(const float* __restrict__ s, unsigned short* __restrict__ d, int n4) {
  int i = blockIdx.x * 256 + threadIdx.x;
  if (i >= n4) return;
  float4 v = reinterpret_cast<const float4*>(s)[i];
  reinterpret_cast<ushort4*>(d)[i] = make_ushort4(f2bf(v.x), f2bf(v.y), f2bf(v.z), f2bf(v.w));
}

// Wc2[d2][j] = Wc[d2][768+j] -> bf16 [768][768]
__global__ void k_cvt_wc2(const float* __restrict__ Wc, unsigned short* __restrict__ d) {
  int i = blockIdx.x * 256 + threadIdx.x;          // 768*192
  if (i >= 768 * 192) return;
  int r = i / 192, c4 = (i - r * 192) * 4;
  float4 v = *reinterpret_cast<const float4*>(Wc + (long long)r * 1536 + 768 + c4);
  reinterpret_cast<ushort4*>(d)[i] = make_ushort4(f2bf(v.x), f2bf(v.y), f2bf(v.z), f2bf(v.w));
}

// WqT[d0][d1] = Wq[d1][d0] -> bf16
__global__ void k_cvt_t(const float* __restrict__ Wq, unsigned short* __restrict__ d) {
  int i = blockIdx.x * 256 + threadIdx.x;          // 768*768
  if (i >= 768 * 768) return;
  int d0 = i / 768, d1 = i - d0 * 768;
  d[i] = f2bf(Wq[(long long)d1 * 768 + d0]);
}

// ---------------- NT GEMM: C[m][n] = sum_k A[m][k]*B[n][k], K=768 ----------------
// MODE 0: Mt (fp32 + bf16) = acc + Wc1[m][n]      (aux = Wc, ld 1536)
// MODE 1: KzT bf16 = mask[b][n] ? acc + bk[m] : 0 (aux = bk)
// MODE 2: Nt  bf16 = acc
// MODE 3: Pt  bf16 = acc
// MODE 4: out fp32 = SCALE*acc + row[b][n]        (aux = row)
template <int MODE>
__global__ __launch_bounds__(256) void gemm_nt(
    const unsigned short* __restrict__ A, long long aStr, int lda,
    const unsigned short* __restrict__ B, long long bStr, int ldb,
    float* __restrict__ Cf, unsigned short* __restrict__ Cbf,
    long long cStr, int ldc,
    const float* __restrict__ aux, const int* __restrict__ mask)
{
  constexpr int BM = 128, BN = 128, BK = 32;
  __shared__ __align__(16) unsigned short As[BM * BK];
  __shared__ __align__(16) unsigned short Bs[BN * BK];

  const int b = blockIdx.z;
  const unsigned short* Ab = A + (long long)b * aStr;
  const unsigned short* Bb = B + (long long)b * bStr;
  const int m0 = blockIdx.y * BM;
  const int n0 = blockIdx.x * BN;

  const int tid = threadIdx.x;
  const int w = tid >> 6, lane = tid & 63;
  const int wr = w >> 1, wc = w & 1;       // 2x2 waves, each 64x64
  const int fr = lane & 15, fq = lane >> 4;

  f32x4 acc[4][4] = {};

  for (int kt = 0; kt < 768; kt += BK) {
    __syncthreads();
    #pragma unroll
    for (int q = 0; q < 2; ++q) {
      int c = q * 256 + w * 64 + lane;     // chunk id: 512 chunks of 16B per tile
      int row = c >> 2, col = (c & 3) << 3;
      const unsigned short* ga = Ab + (long long)(m0 + row) * lda + kt + col;
      __builtin_amdgcn_global_load_lds(
          (const __attribute__((address_space(1))) void*)ga,
          (__attribute__((address_space(3))) void*)(As + (q * 256 + w * 64) * 8), 16, 0, 0);
      const unsigned short* gb = Bb + (long long)(n0 + row) * ldb + kt + col;
      __builtin_amdgcn_global_load_lds(
          (const __attribute__((address_space(1))) void*)gb,
          (__attribute__((address_space(3))) void*)(Bs + (q * 256 + w * 64) * 8), 16, 0, 0);
    }
    __syncthreads();

    short8 af[4], bfr[4];
    #pragma unroll
    for (int i = 0; i < 4; ++i) {
      int r = wr * 64 + i * 16 + fr;
      af[i] = *reinterpret_cast<const short8*>(As + r * BK + fq * 8);
    }
    #pragma unroll
    for (int j = 0; j < 4; ++j) {
      int r = wc * 64 + j * 16 + fr;
      bfr[j] = *reinterpret_cast<const short8*>(Bs + r * BK + fq * 8);
    }
    #pragma unroll
    for (int i = 0; i < 4; ++i)
      #pragma unroll
      for (int j = 0; j < 4; ++j)
        acc[i][j] = __builtin_amdgcn_mfma_f32_16x16x32_bf16(af[i], bfr[j], acc[i][j], 0, 0, 0);
  }

  const int* mb = (MODE == 1) ? (mask + b * 768) : nullptr;
  #pragma unroll
  for (int i = 0; i < 4; ++i)
    #pragma unroll
    for (int j = 0; j < 4; ++j)
      #pragma unroll
      for (int r = 0; r < 4; ++r) {
        int row = m0 + wr * 64 + i * 16 + fq * 4 + r;  // C/D: col=lane&15, row=(lane>>4)*4+r
        int col = n0 + wc * 64 + j * 16 + fr;
        float v = acc[i][j][r];
        if constexpr (MODE == 0) {
          v += aux[(long long)row * 1536 + col];       // + Wc1[d2][k]
          Cf[(long long)row * 768 + col] = v;
          Cbf[(long long)row * 768 + col] = f2bf(v);
        } else if constexpr (MODE == 1) {
          v += aux[row];                               // + bk[d1]
          if (mb[col] == 0) v = 0.0f;                  // zero masked key rows
          Cbf[(long long)b * cStr + (long long)row * ldc + col] = f2bf(v);
        } else if constexpr (MODE == 2 || MODE == 3) {
          Cbf[(long long)b * cStr + (long long)row * ldc + col] = f2bf(v);
        } else {
          Cf[(long long)b * cStr + (long long)row * ldc + col] = v * SCALE + aux[b * 768 + col];
        }
      }
}

// row[b][d2] = bc[d2] - 1e9*sum_{mask==0} Mt[d2][k] + SCALE*sum_d1 bq[d1]*Nt[b][d2][d1]
__global__ void k_row(const float* __restrict__ Mt, const unsigned short* __restrict__ Nt,
                      const int* __restrict__ mask, const float* __restrict__ bq,
                      const float* __restrict__ bc, float* __restrict__ row)
{
  int gw = blockIdx.x * 4 + (threadIdx.x >> 6);   // one wave per (b,d2)
  int lane = threadIdx.x & 63;
  int b = gw / 768;
  int d2 = gw - b * 768;
  if (b >= 8) return;
  const int* mb = mask + b * 768;
  const float* mrow = Mt + (long long)d2 * 768;
  const unsigned short* nrow = Nt + ((long long)b * 768 + d2) * 768;
  float sm = 0.f, sb = 0.f;
  for (int k = lane; k < 768; k += 64) {
    if (mb[k] == 0) sm += mrow[k];
    sb += bq[k] * bf2f(nrow[k]);
  }
  #pragma unroll
  for (int off = 32; off > 0; off >>= 1) {
    sm += __shfl_down(sm, off, 64);
    sb += __shfl_down(sb, off, 64);
  }
  if (lane == 0) row[gw] = bc[d2] - 1e9f * sm + SCALE * sb;
}

extern "C" void kernel_launch(void* const* d_in, const int* in_sizes, int n_in,
                              void* d_out, int out_size, void* d_ws, size_t ws_size,
                              hipStream_t stream)
{
  const float* query = (const float*)d_in[0];
  const float* key   = (const float*)d_in[1];
  const float* prev  = (const float*)d_in[3];
  const int*   mask  = (const int*)d_in[4];
  const float* Wq    = (const float*)d_in[5];
  const float* bq    = (const float*)d_in[6];
  const float* Wk    = (const float*)d_in[7];
  const float* bk    = (const float*)d_in[8];
  const float* Wc    = (const float*)d_in[11];
  const float* bc    = (const float*)d_in[12];
  float* out = (float*)d_out;

  char* p = (char*)d_ws;
  size_t off = 0;
  auto alloc = [&](size_t bytes) {
    char* r = p + off;
    off += (bytes + 255) & ~(size_t)255;
    return r;
  };
  unsigned short* query_bf = (unsigned short*)alloc(12582912ull * 2);
  unsigned short* key_bf   = (unsigned short*)alloc(4718592ull * 2);
  unsigned short* prev_bf  = (unsigned short*)alloc(589824ull * 2);
  unsigned short* Wk_bf    = (unsigned short*)alloc(589824ull * 2);
  unsigned short* Wc2_bf   = (unsigned short*)alloc(589824ull * 2);
  unsigned short* WqT_bf   = (unsigned short*)alloc(589824ull * 2);
  float*          Mt_f     = (float*)alloc(589824ull * 4);
  unsigned short* Mt_bf    = (unsigned short*)alloc(589824ull * 2);
  unsigned short* KzT_bf   = (unsigned short*)alloc(4718592ull * 2);
  unsigned short* Nt_bf    = (unsigned short*)alloc(4718592ull * 2);
  float*          rowv     = (float*)alloc(6144ull * 4);
  unsigned short* Pt_bf    = KzT_bf;   // KzT dead after Nt -> reuse buffer
  (void)ws_size; (void)in_sizes; (void)n_in; (void)out_size;

  // f32 -> bf16 staging
  k_cvt<<<dim3(12288), dim3(256), 0, stream>>>(query, query_bf, 3145728);
  k_cvt<<<dim3(4608),  dim3(256), 0, stream>>>(key, key_bf, 1179648);
  k_cvt<<<dim3(576),   dim3(256), 0, stream>>>(prev, prev_bf, 147456);
  k_cvt<<<dim3(576),   dim3(256), 0, stream>>>(Wk, Wk_bf, 147456);
  k_cvt_wc2<<<dim3(576),  dim3(256), 0, stream>>>(Wc, Wc2_bf);
  k_cvt_t<<<dim3(2304), dim3(256), 0, stream>>>(Wq, WqT_bf);

  // G1: Mt[d2][k] = Wc1[d2][k] + sum_j Wc2[d2][j]*prev[k][j]   (fp32 + bf16 copies)
  gemm_nt<0><<<dim3(6, 6, 1), dim3(256), 0, stream>>>(
      Wc2_bf, 0ll, 768, prev_bf, 0ll, 768, Mt_f, Mt_bf, 0ll, 768, Wc, (const int*)nullptr);
  // G2: KzT[b][d1][k] = mask[b][k] ? (sum_j Wk[d1][j]*key[b][k][j] + bk[d1]) : 0
  gemm_nt<1><<<dim3(6, 6, 8), dim3(256), 0, stream>>>(
      Wk_bf, 0ll, 768, key_bf, 589824ll, 768, (float*)nullptr, KzT_bf, 589824ll, 768, bk, mask);
  // G3: Nt[b][d2][d1] = sum_k Mt[d2][k]*KzT[b][d1][k]   (= N[d1][d2])
  gemm_nt<2><<<dim3(6, 6, 8), dim3(256), 0, stream>>>(
      Mt_bf, 0ll, 768, KzT_bf, 589824ll, 768, (float*)nullptr, Nt_bf, 589824ll, 768,
      (const float*)nullptr, (const int*)nullptr);
  // row constants (needs fp32 Mt and Nt)
  k_row<<<dim3(1536), dim3(256), 0, stream>>>(Mt_f, Nt_bf, mask, bq, bc, rowv);
  // G4: Pt[b][d2][d0] = sum_d1 Nt[b][d2][d1]*WqT[d0][d1]   (= P[d0][d2])
  gemm_nt<3><<<dim3(6, 6, 8), dim3(256), 0, stream>>>(
      Nt_bf, 589824ll, 768, WqT_bf, 0ll, 768, (float*)nullptr, Pt_bf, 589824ll, 768,
      (const float*)nullptr, (const int*)nullptr);
  // G5: out[b][q][d2] = SCALE*sum_d0 query[b][q][d0]*Pt[b][d2][d0] + row[b][d2]
  gemm_nt<4><<<dim3(6, 16, 8), dim3(256), 0, stream>>>(
      query_bf, 1572864ll, 768, Pt_bf, 589824ll, 768, out, (unsigned short*)nullptr,
      1572864ll, 768, rowv, (const int*)nullptr);
}

// Round 3
// 158.341 us; speedup vs baseline: 1.0358x; 1.0358x over previous
//
#include <hip/hip_runtime.h>
#include <hip/hip_bf16.h>

// out[b] = SCALE * query[b] @ P[b] + row[b]
//   P[b] = Wq^T @ N[b],  N[b] = Kz[b]^T @ M,  Kz = mask*(key@Wk^T + bk)
//   M = Wc1^T + prev @ Wc2^T
//   row[b][d] = bc[d] - 1e9*sum_{masked k} M[k][d] + SCALE*(bq@N[b])[d]
// NT GEMMs (both operands K-major), bf16 MFMA 16x16x32, 128x128 tile, BK=32,
// global_load_lds(16B). fp32 inputs staged raw and converted at fragment-read
// (perm truncation on data path; RNE on the Mt/constant path). Bijective XCD
// swizzle (m204) for L2 panel reuse. Granule-XOR LDS swizzle (rule-21 pattern).

typedef __attribute__((ext_vector_type(8))) short short8;
typedef __attribute__((ext_vector_type(4))) float f32x4;
typedef __attribute__((ext_vector_type(4))) unsigned int u32x4;

#define SCALE 0.03608439182435161f   /* 1/sqrt(768) */

__device__ inline unsigned short f2bf(float x) {
  unsigned int u = __builtin_bit_cast(unsigned int, x);
  u = (u + 0x7fffu + ((u >> 16) & 1u)) >> 16;   // RNE
  return (unsigned short)u;
}
__device__ inline float bf2f(unsigned short h) {
  return __builtin_bit_cast(float, ((unsigned int)h) << 16);
}
__device__ inline unsigned int pack_trunc(float hi, float lo) {
  // bf16x2 {hi16(hi), hi16(lo)} in one v_perm_b32
  return __builtin_amdgcn_perm(__builtin_bit_cast(unsigned int, hi),
                               __builtin_bit_cast(unsigned int, lo), 0x07060302u);
}
__device__ inline unsigned int pack_rne(float hi, float lo) {
  return ((unsigned int)f2bf(hi) << 16) | (unsigned int)f2bf(lo);
}

// ---------------- prep kernels ----------------
__global__ void k_cvt(const float* __restrict__ s, unsigned short* __restrict__ d, int n4) {
  int i = blockIdx.x * 256 + threadIdx.x;
  if (i >= n4) return;
  float4 v = reinterpret_cast<const float4*>(s)[i];
  reinterpret_cast<ushort4*>(d)[i] = make_ushort4(f2bf(v.x), f2bf(v.y), f2bf(v.z), f2bf(v.w));
}

// WqT[d0][d1] = Wq[d1][d0] -> bf16, LDS-tiled coalesced transpose
__global__ void k_transpose(const float* __restrict__ src, unsigned short* __restrict__ dst) {
  __shared__ float t[64][65];
  int bx = blockIdx.x * 64, by = blockIdx.y * 64;
  int tx = threadIdx.x & 63, ty = threadIdx.x >> 6;
  #pragma unroll
  for (int i = 0; i < 64; i += 4)
    t[ty + i][tx] = src[(long long)(by + ty + i) * 768 + bx + tx];
  __syncthreads();
  #pragma unroll
  for (int i = 0; i < 64; i += 4)
    dst[(long long)(bx + ty + i) * 768 + by + tx] = f2bf(t[tx][ty + i]);
}

// ---------------- fragment builders ----------------
template <bool RNE>
__device__ inline short8 frag_from_f32(const char* lds, int r, int fq) {
  const f32x4* base = (const f32x4*)lds + r * 8;        // 8 granules (16B) per row
  int g0 = (fq * 2) ^ (r & 7);                          // LDS granule-XOR swizzle
  f32x4 x = base[g0];
  f32x4 y = base[g0 ^ 1];
  unsigned int p0, p1, p2, p3;
  if constexpr (RNE) {
    p0 = pack_rne(x[1], x[0]); p1 = pack_rne(x[3], x[2]);
    p2 = pack_rne(y[1], y[0]); p3 = pack_rne(y[3], y[2]);
  } else {
    p0 = pack_trunc(x[1], x[0]); p1 = pack_trunc(x[3], x[2]);
    p2 = pack_trunc(y[1], y[0]); p3 = pack_trunc(y[3], y[2]);
  }
  u32x4 u = {p0, p1, p2, p3};
  return __builtin_bit_cast(short8, u);
}
__device__ inline short8 frag_from_bf16(const char* lds, int r, int fq) {
  const short8* base = (const short8*)lds + r * 4;      // 4 granules per row
  return base[fq ^ (r & 3)];
}

// ---------------- NT GEMM: C[m][n] = sum_k A[m][k]*B[n][k], K=768 ----------------
// MODE 0: Mt fp32+bf16 = acc + Wc1[m][n] (aux=Wc ld1536), RNE packs
// MODE 1: KzT bf16 = mask[b][n] ? acc + bk[m] : 0
// MODE 2/3: bf16 = acc
// MODE 4: out fp32 = SCALE*acc + row[b][n]
template <int MODE, int AF32, int BF32>
__global__ __launch_bounds__(256) void gemm_nt(
    const void* __restrict__ A, long long aStr, int lda,
    const void* __restrict__ B, long long bStr, int ldb,
    float* __restrict__ Cf, unsigned short* __restrict__ Cbf,
    long long cStr, int ldc,
    const float* __restrict__ aux, const int* __restrict__ mask)
{
  constexpr int BM = 128, BN = 128, BK = 32;
  constexpr int EA = AF32 ? 4 : 2, EB = BF32 ? 4 : 2;
  constexpr int AGR = BK * EA / 16;                 // granules per row: 8 (f32) / 4 (bf16)
  constexpr int BGR = BK * EB / 16;
  constexpr int AG = BM * AGR, BG = BN * BGR;       // total granules per tile
  __shared__ __align__(16) char As[BM * BK * EA];
  __shared__ __align__(16) char Bs[BN * BK * EB];

  // bijective XCD swizzle (m204): each XCD gets a contiguous logical chunk
  const int gx = gridDim.x, gy = gridDim.y;
  const int nwg = gx * gy * (int)gridDim.z;
  int lin = blockIdx.x + gx * (blockIdx.y + gy * blockIdx.z);
  int qq = nwg >> 3, rr = nwg & 7, xcd = lin & 7, loc = lin >> 3;
  int swz = (xcd < rr ? xcd * (qq + 1) : rr * (qq + 1) + (xcd - rr) * qq) + loc;
  int bz = swz / (gx * gy);
  int rem = swz - bz * gx * gy;
  int by = rem / gx, bx = rem - by * gx;

  const int b = bz;
  const char* Ab = (const char*)A + (long long)b * aStr * EA;
  const char* Bb = (const char*)B + (long long)b * bStr * EB;
  const int m0 = by * BM, n0 = bx * BN;

  const int tid = threadIdx.x;
  const int w = tid >> 6, lane = tid & 63;
  const int wr = w >> 1, wc = w & 1;       // 2x2 waves, each 64x64
  const int fr = lane & 15, fq = lane >> 4;

  f32x4 acc[4][4] = {};

  for (int kt = 0; kt < 768; kt += BK) {
    __syncthreads();
    #pragma unroll
    for (int t = 0; t < AG / 256; ++t) {
      int g = t * 256 + tid;
      int row = g / AGR, gc = g - row * AGR;
      int sgc = gc ^ (row & (AGR - 1));              // inverse-swizzled source column
      long long eoff = (long long)(m0 + row) * lda + kt + sgc * (16 / EA);
      __builtin_amdgcn_global_load_lds(
          (const __attribute__((address_space(1))) void*)(Ab + eoff * EA),
          (__attribute__((address_space(3))) void*)(As + g * 16), 16, 0, 0);
    }
    #pragma unroll
    for (int t = 0; t < BG / 256; ++t) {
      int g = t * 256 + tid;
      int row = g / BGR, gc = g - row * BGR;
      int sgc = gc ^ (row & (BGR - 1));
      long long eoff = (long long)(n0 + row) * ldb + kt + sgc * (16 / EB);
      __builtin_amdgcn_global_load_lds(
          (const __attribute__((address_space(1))) void*)(Bb + eoff * EB),
          (__attribute__((address_space(3))) void*)(Bs + g * 16), 16, 0, 0);
    }
    __syncthreads();

    short8 af[4], bfr[4];
    #pragma unroll
    for (int i = 0; i < 4; ++i) {
      int r = wr * 64 + i * 16 + fr;
      if constexpr (AF32) af[i] = frag_from_f32<MODE == 0>(As, r, fq);
      else                af[i] = frag_from_bf16(As, r, fq);
    }
    #pragma unroll
    for (int j = 0; j < 4; ++j) {
      int r = wc * 64 + j * 16 + fr;
      if constexpr (BF32) bfr[j] = frag_from_f32<MODE == 0>(Bs, r, fq);
      else                bfr[j] = frag_from_bf16(Bs, r, fq);
    }
    #pragma unroll
    for (int i = 0; i < 4; ++i)
      #pragma unroll
      for (int j = 0; j < 4; ++j)
        acc[i][j] = __builtin_amdgcn_mfma_f32_16x16x32_bf16(af[i], bfr[j], acc[i][j], 0, 0, 0);
  }

  const int* mb = (MODE == 1) ? (mask + b * 768) : nullptr;
  #pragma unroll
  for (int i = 0; i < 4; ++i)
    #pragma unroll
    for (int j = 0; j < 4; ++j)
      #pragma unroll
      for (int r = 0; r < 4; ++r) {
        int row = m0 + wr * 64 + i * 16 + fq * 4 + r;  // C/D: col=lane&15, row=(lane>>4)*4+r
        int col = n0 + wc * 64 + j * 16 + fr;
        float v = acc[i][j][r];
        if constexpr (MODE == 0) {
          v += aux[(long long)row * 1536 + col];       // + Wc1[d2][k]
          Cf[(long long)row * 768 + col] = v;
          Cbf[(long long)row * 768 + col] = f2bf(v);
        } else if constexpr (MODE == 1) {
          v += aux[row];                               // + bk[d1]
          if (mb[col] == 0) v = 0.0f;                  // zero masked key rows
          Cbf[(long long)b * cStr + (long long)row * ldc + col] = f2bf(v);
        } else if constexpr (MODE == 2 || MODE == 3) {
          Cbf[(long long)b * cStr + (long long)row * ldc + col] = f2bf(v);
        } else {
          Cf[(long long)b * cStr + (long long)row * ldc + col] = v * SCALE + aux[b * 768 + col];
        }
      }
}

// row[b][d2] = bc[d2] - 1e9*sum_{mask==0} Mt[d2][k] + SCALE*sum_d1 bq[d1]*Nt[b][d2][d1]
__global__ void k_row(const float* __restrict__ Mt, const unsigned short* __restrict__ Nt,
                      const int* __restrict__ mask, const float* __restrict__ bq,
                      const float* __restrict__ bc, float* __restrict__ row)
{
  int gw = blockIdx.x * 4 + (threadIdx.x >> 6);   // one wave per (b,d2)
  int lane = threadIdx.x & 63;
  int b = gw / 768;
  int d2 = gw - b * 768;
  if (b >= 8) return;
  const int* mb = mask + b * 768;
  const float* mrow = Mt + (long long)d2 * 768;
  const unsigned short* nrow = Nt + ((long long)b * 768 + d2) * 768;
  float sm = 0.f, sb = 0.f;
  for (int k = lane; k < 768; k += 64) {
    if (mb[k] == 0) sm += mrow[k];
    sb += bq[k] * bf2f(nrow[k]);
  }
  #pragma unroll
  for (int off = 32; off > 0; off >>= 1) {
    sm += __shfl_down(sm, off, 64);
    sb += __shfl_down(sb, off, 64);
  }
  if (lane == 0) row[gw] = bc[d2] - 1e9f * sm + SCALE * sb;
}

extern "C" void kernel_launch(void* const* d_in, const int* in_sizes, int n_in,
                              void* d_out, int out_size, void* d_ws, size_t ws_size,
                              hipStream_t stream)
{
  const float* query = (const float*)d_in[0];
  const float* key   = (const float*)d_in[1];
  const float* prev  = (const float*)d_in[3];
  const int*   mask  = (const int*)d_in[4];
  const float* Wq    = (const float*)d_in[5];
  const float* bq    = (const float*)d_in[6];
  const float* Wk    = (const float*)d_in[7];
  const float* bk    = (const float*)d_in[8];
  const float* Wc    = (const float*)d_in[11];
  const float* bc    = (const float*)d_in[12];
  float* out = (float*)d_out;

  char* p = (char*)d_ws;
  size_t off = 0;
  auto alloc = [&](size_t bytes) {
    char* r = p + off;
    off += (bytes + 255) & ~(size_t)255;
    return r;
  };
  unsigned short* Wk_bf  = (unsigned short*)alloc(589824ull * 2);
  unsigned short* WqT_bf = (unsigned short*)alloc(589824ull * 2);
  float*          Mt_f   = (float*)alloc(589824ull * 4);
  unsigned short* Mt_bf  = (unsigned short*)alloc(589824ull * 2);
  unsigned short* KzT_bf = (unsigned short*)alloc(4718592ull * 2);
  unsigned short* Nt_bf  = (unsigned short*)alloc(4718592ull * 2);
  float*          rowv   = (float*)alloc(6144ull * 4);
  unsigned short* Pt_bf  = KzT_bf;   // KzT dead after Nt -> reuse buffer
  (void)ws_size; (void)in_sizes; (void)n_in; (void)out_size;

  // prep: Wk -> bf16 (RNE), Wq -> WqT bf16 (tiled transpose)
  k_cvt<<<dim3(576), dim3(256), 0, stream>>>(Wk, Wk_bf, 147456);
  k_transpose<<<dim3(12, 12), dim3(256), 0, stream>>>(Wq, WqT_bf);

  // G1: Mt[d2][k] = Wc1[d2][k] + sum_j Wc2[d2][j]*prev[k][j]  (fp32-direct, RNE packs)
  gemm_nt<0, 1, 1><<<dim3(6, 6, 1), dim3(256), 0, stream>>>(
      (const void*)(Wc + 768), 0ll, 1536, (const void*)prev, 0ll, 768,
      Mt_f, Mt_bf, 0ll, 768, Wc, (const int*)nullptr);
  // G2: KzT[b][d1][k] = mask[b][k] ? (sum_j Wk[d1][j]*key[b][k][j] + bk[d1]) : 0
  gemm_nt<1, 0, 1><<<dim3(6, 6, 8), dim3(256), 0, stream>>>(
      (const void*)Wk_bf, 0ll, 768, (const void*)key, 589824ll, 768,
      (float*)nullptr, KzT_bf, 589824ll, 768, bk, mask);
  // G3: Nt[b][d2][d1] = sum_k Mt[d2][k]*KzT[b][d1][k]
  gemm_nt<2, 0, 0><<<dim3(6, 6, 8), dim3(256), 0, stream>>>(
      (const void*)Mt_bf, 0ll, 768, (const void*)KzT_bf, 589824ll, 768,
      (float*)nullptr, Nt_bf, 589824ll, 768, (const float*)nullptr, (const int*)nullptr);
  // row constants (fp32 Mt + Nt)
  k_row<<<dim3(1536), dim3(256), 0, stream>>>(Mt_f, Nt_bf, mask, bq, bc, rowv);
  // G4: Pt[b][d2][d0] = sum_d1 Nt[b][d2][d1]*WqT[d0][d1]
  gemm_nt<3, 0, 0><<<dim3(6, 6, 8), dim3(256), 0, stream>>>(
      (const void*)Nt_bf, 589824ll, 768, (const void*)WqT_bf, 0ll, 768,
      (float*)nullptr, Pt_bf, 589824ll, 768, (const float*)nullptr, (const int*)nullptr);
  // G5: out[b][q][d2] = SCALE*sum_d0 query[b][q][d0]*Pt[b][d2][d0] + row[b][d2]
  gemm_nt<4, 1, 0><<<dim3(6, 16, 8), dim3(256), 0, stream>>>(
      (const void*)query, 1572864ll, 768, (const void*)Pt_bf, 589824ll, 768,
      out, (unsigned short*)nullptr, 1572864ll, 768, rowv, (const int*)nullptr);
}

// Round 4
// 129.821 us; speedup vs baseline: 1.2634x; 1.2197x over previous
//
#include <hip/hip_runtime.h>
#include <hip/hip_bf16.h>

// out[b] = SCALE * query[b] @ P[b] + row[b]
//   P[b] = Wq^T @ N[b],  N[b] = Kz[b]^T @ M,  Kz = mask*(key@Wk^T + bk)
//   M = Wc1^T + prev @ Wc2^T
//   row[b][d] = bc[d] - 1e9*sum_{masked k} M[k][d] + SCALE*(bq@N[b])[d]
// NT GEMMs (both operands K-major), bf16 MFMA 16x16x32, BK=64,
// global_load_lds(16B), rotation LDS swizzle g'=(g+row)&7 (2-way = free),
// bijective XCD swizzle. bf16 inputs pre-converted (staging path stays lean).
// Mask-constant path fp32 (Mt_f / k_row).

typedef __attribute__((ext_vector_type(8))) short short8;
typedef __attribute__((ext_vector_type(4))) float f32x4;

#define SCALE 0.03608439182435161f   /* 1/sqrt(768) */

__device__ inline unsigned short f2bf(float x) {
  unsigned int u = __builtin_bit_cast(unsigned int, x);
  u = (u + 0x7fffu + ((u >> 16) & 1u)) >> 16;   // RNE
  return (unsigned short)u;
}
__device__ inline float bf2f(unsigned short h) {
  return __builtin_bit_cast(float, ((unsigned int)h) << 16);
}

// ---------------- prep kernels ----------------
__global__ void k_cvt(const float* __restrict__ s, unsigned short* __restrict__ d, int n4) {
  int i = blockIdx.x * 256 + threadIdx.x;
  if (i >= n4) return;
  float4 v = reinterpret_cast<const float4*>(s)[i];
  reinterpret_cast<ushort4*>(d)[i] = make_ushort4(f2bf(v.x), f2bf(v.y), f2bf(v.z), f2bf(v.w));
}

// Wc2[d2][j] = Wc[d2][768+j] -> bf16 [768][768]
__global__ void k_cvt_wc2(const float* __restrict__ Wc, unsigned short* __restrict__ d) {
  int i = blockIdx.x * 256 + threadIdx.x;          // 768*192
  if (i >= 768 * 192) return;
  int r = i / 192, c4 = (i - r * 192) * 4;
  float4 v = *reinterpret_cast<const float4*>(Wc + (long long)r * 1536 + 768 + c4);
  reinterpret_cast<ushort4*>(d)[i] = make_ushort4(f2bf(v.x), f2bf(v.y), f2bf(v.z), f2bf(v.w));
}

// WqT[d0][d1] = Wq[d1][d0] -> bf16, LDS-tiled coalesced transpose
__global__ void k_transpose(const float* __restrict__ src, unsigned short* __restrict__ dst) {
  __shared__ float t[64][65];
  int bx = blockIdx.x * 64, by = blockIdx.y * 64;
  int tx = threadIdx.x & 63, ty = threadIdx.x >> 6;
  #pragma unroll
  for (int i = 0; i < 64; i += 4)
    t[ty + i][tx] = src[(long long)(by + ty + i) * 768 + bx + tx];
  __syncthreads();
  #pragma unroll
  for (int i = 0; i < 64; i += 4)
    dst[(long long)(bx + ty + i) * 768 + by + tx] = f2bf(t[tx][ty + i]);
}

// ---------------- NT GEMM: C[m][n] = sum_k A[m][k]*B[n][k], K=768, BK=64 ----------
// MODE 0: Mt fp32+bf16 = acc + Wc1[m][n] (aux=Wc ld1536)
// MODE 1: KzT bf16 = mask[b][n] ? acc + bk[m] : 0
// MODE 2/3: bf16 = acc
// MODE 4: out fp32 = SCALE*acc + row[b][n]
template <int MODE, int BM, int BN>
__global__ __launch_bounds__(256) void gemm_nt(
    const unsigned short* __restrict__ A, long long aStr, int lda,
    const unsigned short* __restrict__ B, long long bStr, int ldb,
    float* __restrict__ Cf, unsigned short* __restrict__ Cbf,
    long long cStr, int ldc,
    const float* __restrict__ aux, const int* __restrict__ mask)
{
  constexpr int BK = 64;                   // 128B rows = 8 granules of 16B
  constexpr int MI = BM / 32;              // per-wave A fragments (2x2 wave grid)
  constexpr int NJ = BN / 32;
  constexpr int AG = BM * 8, BG = BN * 8;  // granules per tile
  __shared__ __align__(16) char As[BM * BK * 2];
  __shared__ __align__(16) char Bs[BN * BK * 2];

  // bijective XCD swizzle (m204): one contiguous logical chunk per XCD
  const int gx = gridDim.x, gy = gridDim.y;
  const int nwg = gx * gy * (int)gridDim.z;
  int lin = blockIdx.x + gx * (blockIdx.y + gy * blockIdx.z);
  int qq = nwg >> 3, rr = nwg & 7, xcd = lin & 7, loc = lin >> 3;
  int swz = (xcd < rr ? xcd * (qq + 1) : rr * (qq + 1) + (xcd - rr) * qq) + loc;
  int bz = swz / (gx * gy);
  int rem = swz - bz * gx * gy;
  int by = rem / gx, bx = rem - by * gx;

  const int b = bz;
  const unsigned short* Ab = A + (long long)b * aStr;
  const unsigned short* Bb = B + (long long)b * bStr;
  const int m0 = by * BM, n0 = bx * BN;

  const int tid = threadIdx.x;
  const int w = tid >> 6, lane = tid & 63;
  const int wr = w >> 1, wc = w & 1;       // 2x2 waves
  const int fr = lane & 15, fq = lane >> 4;

  f32x4 acc[MI][NJ] = {};

  for (int kt = 0; kt < 768; kt += BK) {
    __syncthreads();
    // stage A: linear LDS dest, inverse-rotated source granule (rule 21)
    #pragma unroll
    for (int t = 0; t < AG / 256; ++t) {
      int g = t * 256 + tid;
      int row = g >> 3, s = g & 7;
      int sg = (s - row) & 7;
      const unsigned short* ga = Ab + (long long)(m0 + row) * lda + kt + sg * 8;
      __builtin_amdgcn_global_load_lds(
          (const __attribute__((address_space(1))) void*)ga,
          (__attribute__((address_space(3))) void*)(As + g * 16), 16, 0, 0);
    }
    #pragma unroll
    for (int t = 0; t < BG / 256; ++t) {
      int g = t * 256 + tid;
      int row = g >> 3, s = g & 7;
      int sg = (s - row) & 7;
      const unsigned short* gb = Bb + (long long)(n0 + row) * ldb + kt + sg * 8;
      __builtin_amdgcn_global_load_lds(
          (const __attribute__((address_space(1))) void*)gb,
          (__attribute__((address_space(3))) void*)(Bs + g * 16), 16, 0, 0);
    }
    __syncthreads();

    #pragma unroll
    for (int kk = 0; kk < 2; ++kk) {
      short8 af[MI], bfr[NJ];
      #pragma unroll
      for (int i = 0; i < MI; ++i) {
        int r = wr * (BM / 2) + i * 16 + fr;
        int sgi = ((kk * 4 + fq) + r) & 7;          // rotation-swizzled granule
        af[i] = *reinterpret_cast<const short8*>(As + r * 128 + sgi * 16);
      }
      #pragma unroll
      for (int j = 0; j < NJ; ++j) {
        int r = wc * (BN / 2) + j * 16 + fr;
        int sgj = ((kk * 4 + fq) + r) & 7;
        bfr[j] = *reinterpret_cast<const short8*>(Bs + r * 128 + sgj * 16);
      }
      #pragma unroll
      for (int i = 0; i < MI; ++i)
        #pragma unroll
        for (int j = 0; j < NJ; ++j)
          acc[i][j] = __builtin_amdgcn_mfma_f32_16x16x32_bf16(af[i], bfr[j], acc[i][j], 0, 0, 0);
    }
  }

  const int* mb = (MODE == 1) ? (mask + b * 768) : nullptr;
  #pragma unroll
  for (int i = 0; i < MI; ++i)
    #pragma unroll
    for (int j = 0; j < NJ; ++j)
      #pragma unroll
      for (int r = 0; r < 4; ++r) {
        int row = m0 + wr * (BM / 2) + i * 16 + fq * 4 + r;  // C/D: col=lane&15, row=(lane>>4)*4+r
        int col = n0 + wc * (BN / 2) + j * 16 + fr;
        float v = acc[i][j][r];
        if constexpr (MODE == 0) {
          v += aux[(long long)row * 1536 + col];       // + Wc1[d2][k]
          Cf[(long long)row * 768 + col] = v;
          Cbf[(long long)row * 768 + col] = f2bf(v);
        } else if constexpr (MODE == 1) {
          v += aux[row];                               // + bk[d1]
          if (mb[col] == 0) v = 0.0f;                  // zero masked key rows
          Cbf[(long long)b * cStr + (long long)row * ldc + col] = f2bf(v);
        } else if constexpr (MODE == 2 || MODE == 3) {
          Cbf[(long long)b * cStr + (long long)row * ldc + col] = f2bf(v);
        } else {
          Cf[(long long)b * cStr + (long long)row * ldc + col] = v * SCALE + aux[b * 768 + col];
        }
      }
}

// row[b][d2] = bc[d2] - 1e9*sum_{mask==0} Mt[d2][k] + SCALE*sum_d1 bq[d1]*Nt[b][d2][d1]
__global__ void k_row(const float* __restrict__ Mt, const unsigned short* __restrict__ Nt,
                      const int* __restrict__ mask, const float* __restrict__ bq,
                      const float* __restrict__ bc, float* __restrict__ row)
{
  int gw = blockIdx.x * 4 + (threadIdx.x >> 6);   // one wave per (b,d2)
  int lane = threadIdx.x & 63;
  int b = gw / 768;
  int d2 = gw - b * 768;
  if (b >= 8) return;
  const int* mb = mask + b * 768;
  const float* mrow = Mt + (long long)d2 * 768;
  const unsigned short* nrow = Nt + ((long long)b * 768 + d2) * 768;
  float sm = 0.f, sb = 0.f;
  for (int k = lane; k < 768; k += 64) {
    if (mb[k] == 0) sm += mrow[k];
    sb += bq[k] * bf2f(nrow[k]);
  }
  #pragma unroll
  for (int off = 32; off > 0; off >>= 1) {
    sm += __shfl_down(sm, off, 64);
    sb += __shfl_down(sb, off, 64);
  }
  if (lane == 0) row[gw] = bc[d2] - 1e9f * sm + SCALE * sb;
}

extern "C" void kernel_launch(void* const* d_in, const int* in_sizes, int n_in,
                              void* d_out, int out_size, void* d_ws, size_t ws_size,
                              hipStream_t stream)
{
  const float* query = (const float*)d_in[0];
  const float* key   = (const float*)d_in[1];
  const float* prev  = (const float*)d_in[3];
  const int*   mask  = (const int*)d_in[4];
  const float* Wq    = (const float*)d_in[5];
  const float* bq    = (const float*)d_in[6];
  const float* Wk    = (const float*)d_in[7];
  const float* bk    = (const float*)d_in[8];
  const float* Wc    = (const float*)d_in[11];
  const float* bc    = (const float*)d_in[12];
  float* out = (float*)d_out;

  char* p = (char*)d_ws;
  size_t off = 0;
  auto alloc = [&](size_t bytes) {
    char* r = p + off;
    off += (bytes + 255) & ~(size_t)255;
    return r;
  };
  unsigned short* query_bf = (unsigned short*)alloc(12582912ull * 2);
  unsigned short* key_bf   = (unsigned short*)alloc(4718592ull * 2);
  unsigned short* prev_bf  = (unsigned short*)alloc(589824ull * 2);
  unsigned short* Wk_bf    = (unsigned short*)alloc(589824ull * 2);
  unsigned short* Wc2_bf   = (unsigned short*)alloc(589824ull * 2);
  unsigned short* WqT_bf   = (unsigned short*)alloc(589824ull * 2);
  float*          Mt_f     = (float*)alloc(589824ull * 4);
  unsigned short* Mt_bf    = (unsigned short*)alloc(589824ull * 2);
  unsigned short* KzT_bf   = (unsigned short*)alloc(4718592ull * 2);
  unsigned short* Nt_bf    = (unsigned short*)alloc(4718592ull * 2);
  float*          rowv     = (float*)alloc(6144ull * 4);
  unsigned short* Pt_bf    = KzT_bf;   // KzT dead after G3 -> reuse buffer
  (void)ws_size; (void)in_sizes; (void)n_in; (void)out_size;

  // f32 -> bf16 staging (pure HBM-BW passes, off the GEMM critical path)
  k_cvt<<<dim3(12288), dim3(256), 0, stream>>>(query, query_bf, 3145728);
  k_cvt<<<dim3(4608),  dim3(256), 0, stream>>>(key, key_bf, 1179648);
  k_cvt<<<dim3(576),   dim3(256), 0, stream>>>(prev, prev_bf, 147456);
  k_cvt<<<dim3(576),   dim3(256), 0, stream>>>(Wk, Wk_bf, 147456);
  k_cvt_wc2<<<dim3(576), dim3(256), 0, stream>>>(Wc, Wc2_bf);
  k_transpose<<<dim3(12, 12), dim3(256), 0, stream>>>(Wq, WqT_bf);

  // G1: Mt[d2][k] = Wc1[d2][k] + sum_j Wc2[d2][j]*prev[k][j]
  gemm_nt<0, 64, 128><<<dim3(6, 12, 1), dim3(256), 0, stream>>>(
      Wc2_bf, 0ll, 768, prev_bf, 0ll, 768, Mt_f, Mt_bf, 0ll, 768, Wc, (const int*)nullptr);
  // G2: KzT[b][d1][k] = mask[b][k] ? (sum_j Wk[d1][j]*key[b][k][j] + bk[d1]) : 0
  gemm_nt<1, 64, 128><<<dim3(6, 12, 8), dim3(256), 0, stream>>>(
      Wk_bf, 0ll, 768, key_bf, 589824ll, 768, (float*)nullptr, KzT_bf, 589824ll, 768, bk, mask);
  // G3: Nt[b][d2][d1] = sum_k Mt[d2][k]*KzT[b][d1][k]
  gemm_nt<2, 64, 128><<<dim3(6, 12, 8), dim3(256), 0, stream>>>(
      Mt_bf, 0ll, 768, KzT_bf, 589824ll, 768, (float*)nullptr, Nt_bf, 589824ll, 768,
      (const float*)nullptr, (const int*)nullptr);
  // row constants (fp32 Mt + Nt)
  k_row<<<dim3(1536), dim3(256), 0, stream>>>(Mt_f, Nt_bf, mask, bq, bc, rowv);
  // G4: Pt[b][d2][d0] = sum_d1 Nt[b][d2][d1]*WqT[d0][d1]
  gemm_nt<3, 64, 128><<<dim3(6, 12, 8), dim3(256), 0, stream>>>(
      Nt_bf, 589824ll, 768, WqT_bf, 0ll, 768, (float*)nullptr, Pt_bf, 589824ll, 768,
      (const float*)nullptr, (const int*)nullptr);
  // G5: out[b][q][d2] = SCALE*sum_d0 query[b][q][d0]*Pt[b][d2][d0] + row[b][d2]
  gemm_nt<4, 128, 128><<<dim3(6, 16, 8), dim3(256), 0, stream>>>(
      query_bf, 1572864ll, 768, Pt_bf, 589824ll, 768, out, (unsigned short*)nullptr,
      1572864ll, 768, rowv, (const int*)nullptr);
}

// Round 5
// 127.068 us; speedup vs baseline: 1.2908x; 1.0217x over previous
//
#include <hip/hip_runtime.h>
#include <hip/hip_bf16.h>

// out[b] = SCALE * query[b] @ P[b] + row[b]
//   P[b] = Wq^T @ N[b],  N[b] = Kz[b]^T @ M,  Kz = mask*(key@Wk^T + bk)
//   M = Wc1^T + prev @ Wc2^T
//   row[b][d] = bc[d] - 1e9*sum_{masked k} M[k][d] + SCALE*(bq@N[b])[d]
// NT GEMMs (both operands K-major), bf16 MFMA 16x16x32, BK=64,
// global_load_lds(16B), rotation LDS swizzle g'=(g+row)&7 (measured 0 conflicts),
// bijective XCD swizzle. 64x64 tiles for the 768^3 GEMMs (occupancy/TLP),
// 128x128 for G5. Mask-constant path fp32 (Mt_f / k_row).

typedef __attribute__((ext_vector_type(8))) short short8;
typedef __attribute__((ext_vector_type(4))) float f32x4;

#define SCALE 0.03608439182435161f   /* 1/sqrt(768) */

__device__ inline unsigned short f2bf(float x) {
  unsigned int u = __builtin_bit_cast(unsigned int, x);
  u = (u + 0x7fffu + ((u >> 16) & 1u)) >> 16;   // RNE
  return (unsigned short)u;
}
__device__ inline float bf2f(unsigned short h) {
  return __builtin_bit_cast(float, ((unsigned int)h) << 16);
}

// ---------------- prep kernels ----------------
__global__ void k_cvt(const float* __restrict__ s, unsigned short* __restrict__ d, int n4) {
  int i = blockIdx.x * 256 + threadIdx.x;
  if (i >= n4) return;
  float4 v = reinterpret_cast<const float4*>(s)[i];
  reinterpret_cast<ushort4*>(d)[i] = make_ushort4(f2bf(v.x), f2bf(v.y), f2bf(v.z), f2bf(v.w));
}

// merged small preps: region 0 = Wk cvt, 1 = prev cvt, 2 = Wc2 slice cvt
__global__ void k_prep(const float* __restrict__ Wk, const float* __restrict__ prev,
                       const float* __restrict__ Wc,
                       unsigned short* __restrict__ Wk_bf,
                       unsigned short* __restrict__ prev_bf,
                       unsigned short* __restrict__ Wc2_bf) {
  int g = blockIdx.x;
  int region = g / 576;
  int idx = (g - region * 576) * 256 + threadIdx.x;       // < 147456 float4-groups
  float4 v;
  unsigned short* dst;
  if (region == 0)      { v = reinterpret_cast<const float4*>(Wk)[idx];   dst = Wk_bf; }
  else if (region == 1) { v = reinterpret_cast<const float4*>(prev)[idx]; dst = prev_bf; }
  else {
    int r = idx / 192, c4 = (idx - r * 192) * 4;
    v = *reinterpret_cast<const float4*>(Wc + (long long)r * 1536 + 768 + c4);
    dst = Wc2_bf;
  }
  reinterpret_cast<ushort4*>(dst)[idx] = make_ushort4(f2bf(v.x), f2bf(v.y), f2bf(v.z), f2bf(v.w));
}

// WqT[d0][d1] = Wq[d1][d0] -> bf16, LDS-tiled coalesced transpose
__global__ void k_transpose(const float* __restrict__ src, unsigned short* __restrict__ dst) {
  __shared__ float t[64][65];
  int bx = blockIdx.x * 64, by = blockIdx.y * 64;
  int tx = threadIdx.x & 63, ty = threadIdx.x >> 6;
  #pragma unroll
  for (int i = 0; i < 64; i += 4)
    t[ty + i][tx] = src[(long long)(by + ty + i) * 768 + bx + tx];
  __syncthreads();
  #pragma unroll
  for (int i = 0; i < 64; i += 4)
    dst[(long long)(bx + ty + i) * 768 + by + tx] = f2bf(t[tx][ty + i]);
}

// ---------------- NT GEMM: C[m][n] = sum_k A[m][k]*B[n][k], K=768, BK=64 ----------
// MODE 0: Mt fp32+bf16 = acc + Wc1[m][n] (aux=Wc ld1536)
// MODE 1: KzT bf16 = mask[b][n] ? acc + bk[m] : 0
// MODE 2/3: bf16 = acc
// MODE 4: out fp32 = SCALE*acc + row[b][n]
template <int MODE, int BM, int BN>
__global__ __launch_bounds__(256) void gemm_nt(
    const unsigned short* __restrict__ A, long long aStr, int lda,
    const unsigned short* __restrict__ B, long long bStr, int ldb,
    float* __restrict__ Cf, unsigned short* __restrict__ Cbf,
    long long cStr, int ldc,
    const float* __restrict__ aux, const int* __restrict__ mask)
{
  constexpr int BK = 64;                   // 128B rows = 8 granules of 16B
  constexpr int MI = BM / 32;              // per-wave A fragments (2x2 wave grid)
  constexpr int NJ = BN / 32;
  constexpr int AG = BM * 8, BG = BN * 8;  // granules per tile
  __shared__ __align__(16) char As[BM * BK * 2];
  __shared__ __align__(16) char Bs[BN * BK * 2];

  // bijective XCD swizzle (m204): one contiguous logical chunk per XCD
  const int gx = gridDim.x, gy = gridDim.y;
  const int nwg = gx * gy * (int)gridDim.z;
  int lin = blockIdx.x + gx * (blockIdx.y + gy * blockIdx.z);
  int qq = nwg >> 3, rr = nwg & 7, xcd = lin & 7, loc = lin >> 3;
  int swz = (xcd < rr ? xcd * (qq + 1) : rr * (qq + 1) + (xcd - rr) * qq) + loc;
  int bz = swz / (gx * gy);
  int rem = swz - bz * gx * gy;
  int by = rem / gx, bx = rem - by * gx;

  const int b = bz;
  const unsigned short* Ab = A + (long long)b * aStr;
  const unsigned short* Bb = B + (long long)b * bStr;
  const int m0 = by * BM, n0 = bx * BN;

  const int tid = threadIdx.x;
  const int w = tid >> 6, lane = tid & 63;
  const int wr = w >> 1, wc = w & 1;       // 2x2 waves
  const int fr = lane & 15, fq = lane >> 4;

  f32x4 acc[MI][NJ] = {};

  for (int kt = 0; kt < 768; kt += BK) {
    __syncthreads();
    // stage: linear LDS dest, inverse-rotated source granule (rule 21)
    #pragma unroll
    for (int t = 0; t < AG / 256; ++t) {
      int g = t * 256 + tid;
      int row = g >> 3, s = g & 7;
      int sg = (s - row) & 7;
      const unsigned short* ga = Ab + (long long)(m0 + row) * lda + kt + sg * 8;
      __builtin_amdgcn_global_load_lds(
          (const __attribute__((address_space(1))) void*)ga,
          (__attribute__((address_space(3))) void*)(As + g * 16), 16, 0, 0);
    }
    #pragma unroll
    for (int t = 0; t < BG / 256; ++t) {
      int g = t * 256 + tid;
      int row = g >> 3, s = g & 7;
      int sg = (s - row) & 7;
      const unsigned short* gb = Bb + (long long)(n0 + row) * ldb + kt + sg * 8;
      __builtin_amdgcn_global_load_lds(
          (const __attribute__((address_space(1))) void*)gb,
          (__attribute__((address_space(3))) void*)(Bs + g * 16), 16, 0, 0);
    }
    __syncthreads();

    #pragma unroll
    for (int kk = 0; kk < 2; ++kk) {
      short8 af[MI], bfr[NJ];
      #pragma unroll
      for (int i = 0; i < MI; ++i) {
        int r = wr * (BM / 2) + i * 16 + fr;
        int sgi = ((kk * 4 + fq) + r) & 7;          // rotation-swizzled granule
        af[i] = *reinterpret_cast<const short8*>(As + r * 128 + sgi * 16);
      }
      #pragma unroll
      for (int j = 0; j < NJ; ++j) {
        int r = wc * (BN / 2) + j * 16 + fr;
        int sgj = ((kk * 4 + fq) + r) & 7;
        bfr[j] = *reinterpret_cast<const short8*>(Bs + r * 128 + sgj * 16);
      }
      #pragma unroll
      for (int i = 0; i < MI; ++i)
        #pragma unroll
        for (int j = 0; j < NJ; ++j)
          acc[i][j] = __builtin_amdgcn_mfma_f32_16x16x32_bf16(af[i], bfr[j], acc[i][j], 0, 0, 0);
    }
  }

  const int* mb = (MODE == 1) ? (mask + b * 768) : nullptr;
  #pragma unroll
  for (int i = 0; i < MI; ++i)
    #pragma unroll
    for (int j = 0; j < NJ; ++j)
      #pragma unroll
      for (int r = 0; r < 4; ++r) {
        int row = m0 + wr * (BM / 2) + i * 16 + fq * 4 + r;  // C/D: col=lane&15, row=(lane>>4)*4+r
        int col = n0 + wc * (BN / 2) + j * 16 + fr;
        float v = acc[i][j][r];
        if constexpr (MODE == 0) {
          v += aux[(long long)row * 1536 + col];       // + Wc1[d2][k]
          Cf[(long long)row * 768 + col] = v;
          Cbf[(long long)row * 768 + col] = f2bf(v);
        } else if constexpr (MODE == 1) {
          v += aux[row];                               // + bk[d1]
          if (mb[col] == 0) v = 0.0f;                  // zero masked key rows
          Cbf[(long long)b * cStr + (long long)row * ldc + col] = f2bf(v);
        } else if constexpr (MODE == 2 || MODE == 3) {
          Cbf[(long long)b * cStr + (long long)row * ldc + col] = f2bf(v);
        } else {
          Cf[(long long)b * cStr + (long long)row * ldc + col] = v * SCALE + aux[b * 768 + col];
        }
      }
}

// row[b][d2] = bc[d2] - 1e9*sum_{mask==0} Mt[d2][k] + SCALE*sum_d1 bq[d1]*Nt[b][d2][d1]
__global__ void k_row(const float* __restrict__ Mt, const unsigned short* __restrict__ Nt,
                      const int* __restrict__ mask, const float* __restrict__ bq,
                      const float* __restrict__ bc, float* __restrict__ row)
{
  int gw = blockIdx.x * 4 + (threadIdx.x >> 6);   // one wave per (b,d2)
  int lane = threadIdx.x & 63;
  int b = gw / 768;
  int d2 = gw - b * 768;
  if (b >= 8) return;
  const int* mb = mask + b * 768;
  const float* mrow = Mt + (long long)d2 * 768;
  const unsigned short* nrow = Nt + ((long long)b * 768 + d2) * 768;
  float sm = 0.f, sb = 0.f;
  for (int k = lane; k < 768; k += 64) {
    if (mb[k] == 0) sm += mrow[k];
    sb += bq[k] * bf2f(nrow[k]);
  }
  #pragma unroll
  for (int off = 32; off > 0; off >>= 1) {
    sm += __shfl_down(sm, off, 64);
    sb += __shfl_down(sb, off, 64);
  }
  if (lane == 0) row[gw] = bc[d2] - 1e9f * sm + SCALE * sb;
}

extern "C" void kernel_launch(void* const* d_in, const int* in_sizes, int n_in,
                              void* d_out, int out_size, void* d_ws, size_t ws_size,
                              hipStream_t stream)
{
  const float* query = (const float*)d_in[0];
  const float* key   = (const float*)d_in[1];
  const float* prev  = (const float*)d_in[3];
  const int*   mask  = (const int*)d_in[4];
  const float* Wq    = (const float*)d_in[5];
  const float* bq    = (const float*)d_in[6];
  const float* Wk    = (const float*)d_in[7];
  const float* bk    = (const float*)d_in[8];
  const float* Wc    = (const float*)d_in[11];
  const float* bc    = (const float*)d_in[12];
  float* out = (float*)d_out;

  char* p = (char*)d_ws;
  size_t off = 0;
  auto alloc = [&](size_t bytes) {
    char* r = p + off;
    off += (bytes + 255) & ~(size_t)255;
    return r;
  };
  unsigned short* query_bf = (unsigned short*)alloc(12582912ull * 2);
  unsigned short* key_bf   = (unsigned short*)alloc(4718592ull * 2);
  unsigned short* prev_bf  = (unsigned short*)alloc(589824ull * 2);
  unsigned short* Wk_bf    = (unsigned short*)alloc(589824ull * 2);
  unsigned short* Wc2_bf   = (unsigned short*)alloc(589824ull * 2);
  unsigned short* WqT_bf   = (unsigned short*)alloc(589824ull * 2);
  float*          Mt_f     = (float*)alloc(589824ull * 4);
  unsigned short* Mt_bf    = (unsigned short*)alloc(589824ull * 2);
  unsigned short* KzT_bf   = (unsigned short*)alloc(4718592ull * 2);
  unsigned short* Nt_bf    = (unsigned short*)alloc(4718592ull * 2);
  float*          rowv     = (float*)alloc(6144ull * 4);
  unsigned short* Pt_bf    = KzT_bf;   // KzT dead after G3 -> reuse buffer
  (void)ws_size; (void)in_sizes; (void)n_in; (void)out_size;

  // f32 -> bf16 staging (HBM-BW passes)
  k_cvt<<<dim3(12288), dim3(256), 0, stream>>>(query, query_bf, 3145728);
  k_cvt<<<dim3(4608),  dim3(256), 0, stream>>>(key, key_bf, 1179648);
  k_prep<<<dim3(1728), dim3(256), 0, stream>>>(Wk, prev, Wc, Wk_bf, prev_bf, Wc2_bf);
  k_transpose<<<dim3(12, 12), dim3(256), 0, stream>>>(Wq, WqT_bf);

  // G1: Mt[d2][k] = Wc1[d2][k] + sum_j Wc2[d2][j]*prev[k][j]
  gemm_nt<0, 64, 64><<<dim3(12, 12, 1), dim3(256), 0, stream>>>(
      Wc2_bf, 0ll, 768, prev_bf, 0ll, 768, Mt_f, Mt_bf, 0ll, 768, Wc, (const int*)nullptr);
  // G2: KzT[b][d1][k] = mask[b][k] ? (sum_j Wk[d1][j]*key[b][k][j] + bk[d1]) : 0
  gemm_nt<1, 64, 64><<<dim3(12, 12, 8), dim3(256), 0, stream>>>(
      Wk_bf, 0ll, 768, key_bf, 589824ll, 768, (float*)nullptr, KzT_bf, 589824ll, 768, bk, mask);
  // G3: Nt[b][d2][d1] = sum_k Mt[d2][k]*KzT[b][d1][k]
  gemm_nt<2, 64, 64><<<dim3(12, 12, 8), dim3(256), 0, stream>>>(
      Mt_bf, 0ll, 768, KzT_bf, 589824ll, 768, (float*)nullptr, Nt_bf, 589824ll, 768,
      (const float*)nullptr, (const int*)nullptr);
  // row constants (fp32 Mt + Nt)
  k_row<<<dim3(1536), dim3(256), 0, stream>>>(Mt_f, Nt_bf, mask, bq, bc, rowv);
  // G4: Pt[b][d2][d0] = sum_d1 Nt[b][d2][d1]*WqT[d0][d1]
  gemm_nt<3, 64, 64><<<dim3(12, 12, 8), dim3(256), 0, stream>>>(
      Nt_bf, 589824ll, 768, WqT_bf, 0ll, 768, (float*)nullptr, Pt_bf, 589824ll, 768,
      (const float*)nullptr, (const int*)nullptr);
  // G5: out[b][q][d2] = SCALE*sum_d0 query[b][q][d0]*Pt[b][d2][d0] + row[b][d2]
  gemm_nt<4, 128, 128><<<dim3(6, 16, 8), dim3(256), 0, stream>>>(
      query_bf, 1572864ll, 768, Pt_bf, 589824ll, 768, out, (unsigned short*)nullptr,
      1572864ll, 768, rowv, (const int*)nullptr);
}